// Round 7
// baseline (274.674 us; speedup 1.0000x reference)
//
#include <hip/hip_runtime.h>
#include <hip/hip_bf16.h>

typedef __bf16 bf16x8 __attribute__((ext_vector_type(8)));
typedef unsigned short ushort8 __attribute__((ext_vector_type(8)));
typedef unsigned short ushort4v __attribute__((ext_vector_type(4)));
typedef float f32x4 __attribute__((ext_vector_type(4)));

__device__ __forceinline__ unsigned short f2bf(float f) {
    union { float f; unsigned int i; } v;
    v.f = f;
    unsigned int i = v.i;
    i += 0x7fffu + ((i >> 16) & 1u);  // round-to-nearest-even
    return (unsigned short)(i >> 16);
}

union bfcast { ushort8 u; bf16x8 b; };

__device__ __forceinline__ bf16x8 load_w8_f32(const float* p) {
    const float4 f0 = *(const float4*)p;
    const float4 f1 = *(const float4*)(p + 4);
    bfcast c;
    c.u[0] = f2bf(f0.x); c.u[1] = f2bf(f0.y); c.u[2] = f2bf(f0.z); c.u[3] = f2bf(f0.w);
    c.u[4] = f2bf(f1.x); c.u[5] = f2bf(f1.y); c.u[6] = f2bf(f1.z); c.u[7] = f2bf(f1.w);
    return c.b;
}

__device__ __forceinline__ float fast_tanh(float x) {
    float e = __expf(2.0f * x);
    return 1.0f - 2.0f * __builtin_amdgcn_rcpf(e + 1.0f);
}

// blocks 0..199: enc proj (50 row-tiles x 4 j-quads); 200..251: dec proj (13x4);
// 252..507: W_out fp32 -> bf16, zero-padded to [512][512].
__global__ __launch_bounds__(256, 2) void prep_kernel(
    const float* __restrict__ enc_in, const float* __restrict__ dec_in,
    const float* __restrict__ W_enc,  const float* __restrict__ b_enc,
    const float* __restrict__ W_dec,  const float* __restrict__ b_dec,
    const float* __restrict__ W_out,
    float* __restrict__ enc_proj, float* __restrict__ dec_proj,
    unsigned short* __restrict__ wout_bf)
{
    const int blk = blockIdx.x;
    const int tid = threadIdx.x;

    if (blk >= 252) {  // ---- W_out convert + zero-pad to 512 rows ----
        const int e = (blk - 252) * 1024 + tid * 4;
        ushort4v p;
        if (e < 256000) {  // 500*512 real elements
            const float4 v = *(const float4*)(W_out + e);
            p.x = f2bf(v.x); p.y = f2bf(v.y); p.z = f2bf(v.z); p.w = f2bf(v.w);
        } else {
            p.x = 0; p.y = 0; p.z = 0; p.w = 0;
        }
        *(ushort4v*)(wout_bf + e) = p;
        return;
    }

    // ---- projection: 32 rows x 128 cols per block ----
    const float *A, *W, *bias; float* outp; int Ma, t, jq;
    if (blk < 200) { A = enc_in; W = W_enc; bias = b_enc; outp = enc_proj;
                     Ma = 1600; t = blk >> 2; jq = blk & 3; }
    else           { const int b2 = blk - 200;
                     A = dec_in; W = W_dec; bias = b_dec; outp = dec_proj;
                     Ma = 400;  t = b2 >> 2;  jq = b2 & 3; }
    const int r0 = t * 32;

    __shared__ unsigned short tile[32 * 520];
    {   // stage A fp32->bf16: 8 threads per row
        const int row = tid >> 3, q = tid & 7;
        int gr = r0 + row;
        if (gr >= Ma) gr = Ma - 1;
        const float* src = A + (size_t)gr * 512;
        ushort8* dst = (ushort8*)(tile + row * 520);
        #pragma unroll
        for (int i = 0; i < 8; ++i) {
            const int c = q + i * 8;
            const int k = c * 8;
            const float4 a0 = *(const float4*)(src + k);
            const float4 a1 = *(const float4*)(src + k + 4);
            bfcast pk;
            pk.u[0] = f2bf(a0.x); pk.u[1] = f2bf(a0.y); pk.u[2] = f2bf(a0.z); pk.u[3] = f2bf(a0.w);
            pk.u[4] = f2bf(a1.x); pk.u[5] = f2bf(a1.y); pk.u[6] = f2bf(a1.z); pk.u[7] = f2bf(a1.w);
            dst[c] = pk.u;
        }
    }
    __syncthreads();

    const int wave = tid >> 6, lane = tid & 63;
    const int lrow = lane & 15;
    const int lk8  = (lane >> 4) * 8;
    const int j0   = jq * 128 + wave * 32;

    f32x4 acc[2][2];
    #pragma unroll
    for (int mi = 0; mi < 2; ++mi)
        #pragma unroll
        for (int ji = 0; ji < 2; ++ji)
            acc[mi][ji] = (f32x4){0.f, 0.f, 0.f, 0.f};

    const unsigned short* abase = tile + lrow * 520 + lk8;
    const float* wb0 = W + (size_t)(j0 + lrow) * 512 + lk8;
    const float* wb1 = wb0 + 16 * 512;

    #pragma unroll
    for (int kk = 0; kk < 512; kk += 32) {
        const bf16x8 a0 = *(const bf16x8*)(abase + kk);
        const bf16x8 a1 = *(const bf16x8*)(abase + 16 * 520 + kk);
        const bf16x8 b0 = load_w8_f32(wb0 + kk);
        const bf16x8 b1 = load_w8_f32(wb1 + kk);
        acc[0][0] = __builtin_amdgcn_mfma_f32_16x16x32_bf16(a0, b0, acc[0][0], 0, 0, 0);
        acc[0][1] = __builtin_amdgcn_mfma_f32_16x16x32_bf16(a0, b1, acc[0][1], 0, 0, 0);
        acc[1][0] = __builtin_amdgcn_mfma_f32_16x16x32_bf16(a1, b0, acc[1][0], 0, 0, 0);
        acc[1][1] = __builtin_amdgcn_mfma_f32_16x16x32_bf16(a1, b1, acc[1][1], 0, 0, 0);
    }

    const int crow = (lane >> 4) * 4;
    const int ccol = lane & 15;
    #pragma unroll
    for (int ji = 0; ji < 2; ++ji) {
        const int col = j0 + ji * 16 + ccol;
        const float bv = bias[col];
        #pragma unroll
        for (int mi = 0; mi < 2; ++mi)
            #pragma unroll
            for (int rg = 0; rg < 4; ++rg) {
                const int gr = r0 + mi * 16 + crow + rg;
                if (gr < Ma) outp[(size_t)gr * 512 + col] = acc[mi][ji][rg] + bv;
            }
    }
}

// out[r, v] = sum_k tanh(enc[n,t,k] + dec[n,u,k]) * Wout[v,k] + bout[v]
// Round-5 post-mortem: occupancy/regs/stores/stagger all falsified; the kernel
// was 3 serialized barrier-phases with disjoint pipe usage (tanh=VALU,
// K-loop=MFMA, epilogue=stores), so every pipe idles 2/3 of the time
// (MfmaUtil pinned at 16% across all variants).
// This version DISSOLVES the phases: K split into 4 chunks of 128; the tanh
// for chunk c+1 is source-interleaved piece-by-piece with the MFMA steps of
// chunk c (double-buffered LDS, one barrier per chunk) so VALU work fills
// MFMA/load stall slots. 512 thr = 8 waves, BM=64, acc[4][4]=64 AGPR,
// <=128 regs + 34.8 KB LDS -> 2 blocks/CU: one block's store-drain epilogue
// overlaps the other block's compute.
__global__ __launch_bounds__(512, 4) void joiner_kernel(
    const float* __restrict__ encp,          // 1600 x 512 f32 (ws)
    const float* __restrict__ decp,          // 400 x 512 f32 (ws)
    const unsigned short* __restrict__ Wout, // 512 x 512 bf16, rows >=500 zero (ws)
    const float* __restrict__ bout,          // 500 f32
    float* __restrict__ out)                 // 80000 x 500 f32
{
    __shared__ unsigned short buf[2][64 * 136];  // 34,816 B; epilogue reuses as 16x516 f32
    const int tid = threadIdx.x;
    const int r0 = blockIdx.x * 64;

    // tanh producer mapping: 8 threads per row, 16 k-elems per thread per chunk
    const int trow = tid >> 3, tq = tid & 7;
    const int r_ = r0 + trow;
    const int n_ = r_ / 10000;
    const int rem_ = r_ % 10000;
    const int t_ = rem_ / 50;
    const int u_ = rem_ - t_ * 50;
    const float* erow = encp + (size_t)(n_ * 200 + t_) * 512 + tq * 16;
    const float* drow = decp + (size_t)(n_ * 50 + u_) * 512 + tq * 16;

    // prologue: tanh chunk 0 -> buf[0]
    {
        unsigned short* nb = &buf[0][0] + trow * 136 + tq * 16;
        #pragma unroll
        for (int p = 0; p < 4; ++p) {
            const float4 ev = *(const float4*)(erow + p * 4);
            const float4 dv = *(const float4*)(drow + p * 4);
            ushort4v pk;
            pk.x = f2bf(fast_tanh(ev.x + dv.x));
            pk.y = f2bf(fast_tanh(ev.y + dv.y));
            pk.z = f2bf(fast_tanh(ev.z + dv.z));
            pk.w = f2bf(fast_tanh(ev.w + dv.w));
            *(ushort4v*)(nb + p * 4) = pk;
        }
    }
    __syncthreads();

    const int wave = tid >> 6, lane = tid & 63;
    const int lrow = lane & 15;
    const int lk8  = (lane >> 4) * 8;
    const int v0   = wave * 64;

    f32x4 acc[4][4];
    #pragma unroll
    for (int mi = 0; mi < 4; ++mi)
        #pragma unroll
        for (int ji = 0; ji < 4; ++ji)
            acc[mi][ji] = (f32x4){0.f, 0.f, 0.f, 0.f};

    const unsigned short* wrow[4];
    #pragma unroll
    for (int ji = 0; ji < 4; ++ji)
        wrow[ji] = Wout + (size_t)(v0 + ji * 16 + lrow) * 512 + lk8;

    // 4 K-chunks of 128; tanh(c+1) interleaved with MFMA(c); 1 barrier/chunk
    #pragma unroll
    for (int c = 0; c < 4; ++c) {
        const unsigned short* cb = &buf[c & 1][0] + lrow * 136 + lk8;
        unsigned short* nb = &buf[(c + 1) & 1][0] + trow * 136 + tq * 16;
        const int co = c * 128;           // B k-offset for this chunk
        const int go = (c + 1) * 128;     // tanh global-k offset for next chunk
        #pragma unroll
        for (int kk = 0; kk < 4; ++kk) {
            // --- producer piece kk of chunk c+1 (4 elems/thread) ---
            if (c < 3) {
                const float4 ev = *(const float4*)(erow + go + kk * 4);
                const float4 dv = *(const float4*)(drow + go + kk * 4);
                ushort4v pk;
                pk.x = f2bf(fast_tanh(ev.x + dv.x));
                pk.y = f2bf(fast_tanh(ev.y + dv.y));
                pk.z = f2bf(fast_tanh(ev.z + dv.z));
                pk.w = f2bf(fast_tanh(ev.w + dv.w));
                *(ushort4v*)(nb + kk * 4) = pk;
            }
            // --- consumer step kk of chunk c: 4 B-loads, 4 A-frags, 16 MFMA ---
            bf16x8 b[4];
            #pragma unroll
            for (int ji = 0; ji < 4; ++ji)
                b[ji] = *(const bf16x8*)(wrow[ji] + co + kk * 32);
            bf16x8 a[4];
            #pragma unroll
            for (int mi = 0; mi < 4; ++mi)
                a[mi] = *(const bf16x8*)(cb + mi * 16 * 136 + kk * 32);
            #pragma unroll
            for (int mi = 0; mi < 4; ++mi)
                #pragma unroll
                for (int ji = 0; ji < 4; ++ji)
                    acc[mi][ji] = __builtin_amdgcn_mfma_f32_16x16x32_bf16(
                        a[mi], b[ji], acc[mi][ji], 0, 0, 0);
        }
        __syncthreads();
    }

    // epilogue: four 16-row quarters through LDS, then contiguous float4 stores
    float* ob = (float*)&buf[0][0];          // 16 rows x stride 516 f32 (33,024 B)
    const int crow = (lane >> 4) * 4;
    const int ccol = lane & 15;
    const int srow = tid >> 5, sslot = tid & 31;   // 16 rows x 32 slots
    #pragma unroll
    for (int h = 0; h < 4; ++h) {
        if (h) __syncthreads();   // prev quarter's LDS reads done
        #pragma unroll
        for (int ji = 0; ji < 4; ++ji) {
            const int v = v0 + ji * 16 + ccol;
            const float bv = (v < 500) ? bout[v] : 0.f;
            #pragma unroll
            for (int rg = 0; rg < 4; ++rg)
                ob[(crow + rg) * 516 + v] = acc[h][ji][rg] + bv;
        }
        __syncthreads();
        const size_t gr = (size_t)(r0 + h * 16 + srow);
        const float* src = ob + srow * 516;
        float* drw = out + gr * 500;
        #pragma unroll
        for (int i = 0; i < 4; ++i) {
            const int c2 = sslot + 32 * i;
            if (c2 < 125)
                *(float4*)(drw + c2 * 4) = *(const float4*)(src + c2 * 4);
        }
    }
}

extern "C" void kernel_launch(void* const* d_in, const int* in_sizes, int n_in,
                              void* d_out, int out_size, void* d_ws, size_t ws_size,
                              hipStream_t stream) {
    (void)in_sizes; (void)n_in; (void)out_size; (void)ws_size;
    const float* enc_in = (const float*)d_in[0]; // 8x200x512 f32
    const float* dec_in = (const float*)d_in[1]; // 8x50x512 f32
    const float* W_enc  = (const float*)d_in[2]; // 512x512 f32
    const float* b_enc  = (const float*)d_in[3]; // 512 f32
    const float* W_dec  = (const float*)d_in[4]; // 512x512 f32
    const float* b_dec  = (const float*)d_in[5]; // 512 f32
    const float* W_out  = (const float*)d_in[6]; // 500x512 f32
    const float* b_out  = (const float*)d_in[7]; // 500 f32
    float* out = (float*)d_out;                  // 8x200x50x500 f32

    float* ws = (float*)d_ws;
    float* enc_proj = ws;                                      // 1600*512 f32
    float* dec_proj = ws + 819200;                             // 400*512 f32
    unsigned short* wout_bf = (unsigned short*)(ws + 1024000); // 512*512 bf16 (padded)

    hipLaunchKernelGGL(prep_kernel, dim3(508), dim3(256), 0, stream,
                       enc_in, dec_in, W_enc, b_enc, W_dec, b_dec, W_out,
                       enc_proj, dec_proj, wout_bf);
    hipLaunchKernelGGL(joiner_kernel, dim3(1250), dim3(512), 0, stream,
                       enc_proj, dec_proj, wout_bf, b_out, out);
}

// Round 8
// 272.345 us; speedup vs baseline: 1.0086x; 1.0086x over previous
//
#include <hip/hip_runtime.h>
#include <hip/hip_bf16.h>

typedef __bf16 bf16x8 __attribute__((ext_vector_type(8)));
typedef unsigned short ushort8 __attribute__((ext_vector_type(8)));
typedef unsigned short ushort4v __attribute__((ext_vector_type(4)));
typedef float f32x4 __attribute__((ext_vector_type(4)));

__device__ __forceinline__ unsigned short f2bf(float f) {
    union { float f; unsigned int i; } v;
    v.f = f;
    unsigned int i = v.i;
    i += 0x7fffu + ((i >> 16) & 1u);  // round-to-nearest-even
    return (unsigned short)(i >> 16);
}

union bfcast { ushort8 u; bf16x8 b; };

__device__ __forceinline__ bf16x8 load_w8_f32(const float* p) {
    const float4 f0 = *(const float4*)p;
    const float4 f1 = *(const float4*)(p + 4);
    bfcast c;
    c.u[0] = f2bf(f0.x); c.u[1] = f2bf(f0.y); c.u[2] = f2bf(f0.z); c.u[3] = f2bf(f0.w);
    c.u[4] = f2bf(f1.x); c.u[5] = f2bf(f1.y); c.u[6] = f2bf(f1.z); c.u[7] = f2bf(f1.w);
    return c.b;
}

__device__ __forceinline__ float fast_tanh(float x) {
    float e = __expf(2.0f * x);
    return 1.0f - 2.0f * __builtin_amdgcn_rcpf(e + 1.0f);
}

// blocks 0..199: enc proj (50 row-tiles x 4 j-quads); 200..251: dec proj (13x4);
// 252..507: W_out fp32 -> bf16, zero-padded to [512][512].
__global__ __launch_bounds__(256, 2) void prep_kernel(
    const float* __restrict__ enc_in, const float* __restrict__ dec_in,
    const float* __restrict__ W_enc,  const float* __restrict__ b_enc,
    const float* __restrict__ W_dec,  const float* __restrict__ b_dec,
    const float* __restrict__ W_out,
    float* __restrict__ enc_proj, float* __restrict__ dec_proj,
    unsigned short* __restrict__ wout_bf)
{
    const int blk = blockIdx.x;
    const int tid = threadIdx.x;

    if (blk >= 252) {  // ---- W_out convert + zero-pad to 512 rows ----
        const int e = (blk - 252) * 1024 + tid * 4;
        ushort4v p;
        if (e < 256000) {  // 500*512 real elements
            const float4 v = *(const float4*)(W_out + e);
            p.x = f2bf(v.x); p.y = f2bf(v.y); p.z = f2bf(v.z); p.w = f2bf(v.w);
        } else {
            p.x = 0; p.y = 0; p.z = 0; p.w = 0;
        }
        *(ushort4v*)(wout_bf + e) = p;
        return;
    }

    // ---- projection: 32 rows x 128 cols per block ----
    const float *A, *W, *bias; float* outp; int Ma, t, jq;
    if (blk < 200) { A = enc_in; W = W_enc; bias = b_enc; outp = enc_proj;
                     Ma = 1600; t = blk >> 2; jq = blk & 3; }
    else           { const int b2 = blk - 200;
                     A = dec_in; W = W_dec; bias = b_dec; outp = dec_proj;
                     Ma = 400;  t = b2 >> 2;  jq = b2 & 3; }
    const int r0 = t * 32;

    __shared__ unsigned short tile[32 * 520];
    {   // stage A fp32->bf16: 8 threads per row
        const int row = tid >> 3, q = tid & 7;
        int gr = r0 + row;
        if (gr >= Ma) gr = Ma - 1;
        const float* src = A + (size_t)gr * 512;
        ushort8* dst = (ushort8*)(tile + row * 520);
        #pragma unroll
        for (int i = 0; i < 8; ++i) {
            const int c = q + i * 8;
            const int k = c * 8;
            const float4 a0 = *(const float4*)(src + k);
            const float4 a1 = *(const float4*)(src + k + 4);
            bfcast pk;
            pk.u[0] = f2bf(a0.x); pk.u[1] = f2bf(a0.y); pk.u[2] = f2bf(a0.z); pk.u[3] = f2bf(a0.w);
            pk.u[4] = f2bf(a1.x); pk.u[5] = f2bf(a1.y); pk.u[6] = f2bf(a1.z); pk.u[7] = f2bf(a1.w);
            dst[c] = pk.u;
        }
    }
    __syncthreads();

    const int wave = tid >> 6, lane = tid & 63;
    const int lrow = lane & 15;
    const int lk8  = (lane >> 4) * 8;
    const int j0   = jq * 128 + wave * 32;

    f32x4 acc[2][2];
    #pragma unroll
    for (int mi = 0; mi < 2; ++mi)
        #pragma unroll
        for (int ji = 0; ji < 2; ++ji)
            acc[mi][ji] = (f32x4){0.f, 0.f, 0.f, 0.f};

    const unsigned short* abase = tile + lrow * 520 + lk8;
    const float* wb0 = W + (size_t)(j0 + lrow) * 512 + lk8;
    const float* wb1 = wb0 + 16 * 512;

    #pragma unroll
    for (int kk = 0; kk < 512; kk += 32) {
        const bf16x8 a0 = *(const bf16x8*)(abase + kk);
        const bf16x8 a1 = *(const bf16x8*)(abase + 16 * 520 + kk);
        const bf16x8 b0 = load_w8_f32(wb0 + kk);
        const bf16x8 b1 = load_w8_f32(wb1 + kk);
        acc[0][0] = __builtin_amdgcn_mfma_f32_16x16x32_bf16(a0, b0, acc[0][0], 0, 0, 0);
        acc[0][1] = __builtin_amdgcn_mfma_f32_16x16x32_bf16(a0, b1, acc[0][1], 0, 0, 0);
        acc[1][0] = __builtin_amdgcn_mfma_f32_16x16x32_bf16(a1, b0, acc[1][0], 0, 0, 0);
        acc[1][1] = __builtin_amdgcn_mfma_f32_16x16x32_bf16(a1, b1, acc[1][1], 0, 0, 0);
    }

    const int crow = (lane >> 4) * 4;
    const int ccol = lane & 15;
    #pragma unroll
    for (int ji = 0; ji < 2; ++ji) {
        const int col = j0 + ji * 16 + ccol;
        const float bv = bias[col];
        #pragma unroll
        for (int mi = 0; mi < 2; ++mi)
            #pragma unroll
            for (int rg = 0; rg < 4; ++rg) {
                const int gr = r0 + mi * 16 + crow + rg;
                if (gr < Ma) outp[(size_t)gr * 512 + col] = acc[mi][ji][rg] + bv;
            }
    }
}

// out[r, v] = sum_k tanh(enc[n,t,k] + dec[n,u,k]) * Wout[v,k] + bout[v]
// 512 thr = 8 waves; BM=128 rows/block (625 blocks, exact); wave w owns v in
// [w*64, w*64+64), acc[8][4] (128 AGPRs). K-loop identical to the round-4
// 103.5 us kernel (best measured).
// Round-7 post-mortem: VALU-busy-time (~19-20 us) and MFMA-busy-time
// (~16.5 us) are CONSTANT across all 6 variants -- only idle gaps vary, and
// TLP doesn't shrink them -> the idle is globally correlated. This round
// removes the epilogue barrier convoy: stores go DIRECTLY from accumulators,
// per-wave, barrier-free (C-fragment layout gives 16 lanes x 4B = 64B
// contiguous groups; adjacent ji-tiles fill each row in-window so L2 merges
// to full lines). Each wave streams stores as soon as ITS K-loop ends,
// overlapping other waves' MFMA instead of waiting for the whole block.
__global__ __launch_bounds__(512, 2) void joiner_kernel(
    const float* __restrict__ encp,          // 1600 x 512 f32 (ws)
    const float* __restrict__ decp,          // 400 x 512 f32 (ws)
    const unsigned short* __restrict__ Wout, // 512 x 512 bf16, rows >=500 zero (ws)
    const float* __restrict__ bout,          // 500 f32
    float* __restrict__ out)                 // 80000 x 500 f32
{
    __shared__ unsigned short tile[128 * 520];   // 133,120 B
    const int tid = threadIdx.x;
    const int r0 = blockIdx.x * 128;

    {   // phase 1: x-tile = tanh(enc+dec) -> bf16, 8 threads/row, 2 row-halves
        const int rowb = tid >> 3, q = tid & 7;
        #pragma unroll
        for (int half = 0; half < 2; ++half) {
            const int row = rowb + half * 64;
            const int r = r0 + row;
            const int n = r / 10000;
            const int rem = r % 10000;
            const int t = rem / 50;
            const int u = rem - t * 50;
            const float* erow = encp + (size_t)(n * 200 + t) * 512;
            const float* drow = decp + (size_t)(n * 50 + u) * 512;
            ushort8* dst = (ushort8*)(tile + row * 520);
            #pragma unroll
            for (int i = 0; i < 8; ++i) {
                const int c = q + i * 8;
                const int k = c * 8;
                const float4 ev0 = *(const float4*)(erow + k);
                const float4 ev1 = *(const float4*)(erow + k + 4);
                const float4 dv0 = *(const float4*)(drow + k);
                const float4 dv1 = *(const float4*)(drow + k + 4);
                float xs[8] = {ev0.x + dv0.x, ev0.y + dv0.y, ev0.z + dv0.z, ev0.w + dv0.w,
                               ev1.x + dv1.x, ev1.y + dv1.y, ev1.z + dv1.z, ev1.w + dv1.w};
                bfcast pk;
                #pragma unroll
                for (int j = 0; j < 8; ++j) pk.u[j] = f2bf(fast_tanh(xs[j]));
                dst[c] = pk.u;
            }
        }
    }
    __syncthreads();

    const int wave = tid >> 6, lane = tid & 63;
    const int lrow = lane & 15;
    const int lk8  = (lane >> 4) * 8;
    const int v0   = wave * 64;

    f32x4 acc[8][4];
    #pragma unroll
    for (int mi = 0; mi < 8; ++mi)
        #pragma unroll
        for (int ji = 0; ji < 4; ++ji)
            acc[mi][ji] = (f32x4){0.f, 0.f, 0.f, 0.f};

    const unsigned short* wrow[4];
    #pragma unroll
    for (int ji = 0; ji < 4; ++ji)
        wrow[ji] = Wout + (size_t)(v0 + ji * 16 + lrow) * 512 + lk8;
    const unsigned short* abase = tile + lrow * 520 + lk8;

    // depth-2 software pipeline on B (L2-resident Wout panel, read once/wave)
    bf16x8 breg[2][4];
    #pragma unroll
    for (int ji = 0; ji < 4; ++ji) breg[0][ji] = *(const bf16x8*)(wrow[ji]);
    #pragma unroll
    for (int ji = 0; ji < 4; ++ji) breg[1][ji] = *(const bf16x8*)(wrow[ji] + 32);

    #pragma unroll
    for (int kk = 0; kk < 16; ++kk) {
        bf16x8 bn[4];
        if (kk < 14) {
            #pragma unroll
            for (int ji = 0; ji < 4; ++ji)
                bn[ji] = *(const bf16x8*)(wrow[ji] + (kk + 2) * 32);
        }
        #pragma unroll
        for (int mi = 0; mi < 8; ++mi) {
            const bf16x8 a = *(const bf16x8*)(abase + mi * 16 * 520 + kk * 32);
            #pragma unroll
            for (int ji = 0; ji < 4; ++ji)
                acc[mi][ji] = __builtin_amdgcn_mfma_f32_16x16x32_bf16(
                    a, breg[kk & 1][ji], acc[mi][ji], 0, 0, 0);
        }
        if (kk < 14) {
            #pragma unroll
            for (int ji = 0; ji < 4; ++ji) breg[kk & 1][ji] = bn[ji];
        }
    }

    // epilogue: DIRECT per-wave stores from accumulators, no barriers, no LDS.
    // Lane layout: v = v0 + ji*16 + (lane&15), row = mi*16 + (lane>>4)*4 + rg.
    // Each 16-lane group stores 64B contiguous; ji-tiles complete the row
    // segment so L2 write-merges to full lines.
    {
        const int crow = (lane >> 4) * 4;
        const int ccol = lane & 15;
        float bv[4];
        #pragma unroll
        for (int ji = 0; ji < 4; ++ji) {
            const int v = v0 + ji * 16 + ccol;
            bv[ji] = (v < 500) ? bout[v] : 0.f;
        }
        #pragma unroll
        for (int mi = 0; mi < 8; ++mi) {
            const int rbase = r0 + mi * 16 + crow;
            #pragma unroll
            for (int rg = 0; rg < 4; ++rg) {
                float* orow = out + (size_t)(rbase + rg) * 500;
                #pragma unroll
                for (int ji = 0; ji < 4; ++ji) {
                    const int v = v0 + ji * 16 + ccol;
                    if (v < 500)
                        orow[v] = acc[mi][ji][rg] + bv[ji];
                }
            }
        }
    }
}

extern "C" void kernel_launch(void* const* d_in, const int* in_sizes, int n_in,
                              void* d_out, int out_size, void* d_ws, size_t ws_size,
                              hipStream_t stream) {
    (void)in_sizes; (void)n_in; (void)out_size; (void)ws_size;
    const float* enc_in = (const float*)d_in[0]; // 8x200x512 f32
    const float* dec_in = (const float*)d_in[1]; // 8x50x512 f32
    const float* W_enc  = (const float*)d_in[2]; // 512x512 f32
    const float* b_enc  = (const float*)d_in[3]; // 512 f32
    const float* W_dec  = (const float*)d_in[4]; // 512x512 f32
    const float* b_dec  = (const float*)d_in[5]; // 512 f32
    const float* W_out  = (const float*)d_in[6]; // 500x512 f32
    const float* b_out  = (const float*)d_in[7]; // 500 f32
    float* out = (float*)d_out;                  // 8x200x50x500 f32

    float* ws = (float*)d_ws;
    float* enc_proj = ws;                                      // 1600*512 f32
    float* dec_proj = ws + 819200;                             // 400*512 f32
    unsigned short* wout_bf = (unsigned short*)(ws + 1024000); // 512*512 bf16 (padded)

    hipLaunchKernelGGL(prep_kernel, dim3(508), dim3(256), 0, stream,
                       enc_in, dec_in, W_enc, b_enc, W_dec, b_dec, W_out,
                       enc_proj, dec_proj, wout_bf);
    hipLaunchKernelGGL(joiner_kernel, dim3(625), dim3(512), 0, stream,
                       enc_proj, dec_proj, wout_bf, b_out, out);
}

// Round 9
// 262.771 us; speedup vs baseline: 1.0453x; 1.0364x over previous
//
#include <hip/hip_runtime.h>
#include <hip/hip_bf16.h>

typedef __bf16 bf16x8 __attribute__((ext_vector_type(8)));
typedef unsigned short ushort8 __attribute__((ext_vector_type(8)));
typedef unsigned short ushort4v __attribute__((ext_vector_type(4)));
typedef float f32x4 __attribute__((ext_vector_type(4)));

__device__ __forceinline__ unsigned short f2bf(float f) {
    union { float f; unsigned int i; } v;
    v.f = f;
    unsigned int i = v.i;
    i += 0x7fffu + ((i >> 16) & 1u);  // round-to-nearest-even
    return (unsigned short)(i >> 16);
}

union bfcast { ushort8 u; bf16x8 b; };

__device__ __forceinline__ bf16x8 load_w8_f32(const float* p) {
    const float4 f0 = *(const float4*)p;
    const float4 f1 = *(const float4*)(p + 4);
    bfcast c;
    c.u[0] = f2bf(f0.x); c.u[1] = f2bf(f0.y); c.u[2] = f2bf(f0.z); c.u[3] = f2bf(f0.w);
    c.u[4] = f2bf(f1.x); c.u[5] = f2bf(f1.y); c.u[6] = f2bf(f1.z); c.u[7] = f2bf(f1.w);
    return c.b;
}

__device__ __forceinline__ float fast_tanh(float x) {
    float e = __expf(2.0f * x);
    return 1.0f - 2.0f * __builtin_amdgcn_rcpf(e + 1.0f);
}

// blocks 0..199: enc proj (50 row-tiles x 4 j-quads); 200..251: dec proj (13x4);
// 252..507: W_out fp32 -> bf16, zero-padded to [512][512].
__global__ __launch_bounds__(256, 2) void prep_kernel(
    const float* __restrict__ enc_in, const float* __restrict__ dec_in,
    const float* __restrict__ W_enc,  const float* __restrict__ b_enc,
    const float* __restrict__ W_dec,  const float* __restrict__ b_dec,
    const float* __restrict__ W_out,
    float* __restrict__ enc_proj, float* __restrict__ dec_proj,
    unsigned short* __restrict__ wout_bf)
{
    const int blk = blockIdx.x;
    const int tid = threadIdx.x;

    if (blk >= 252) {  // ---- W_out convert + zero-pad to 512 rows ----
        const int e = (blk - 252) * 1024 + tid * 4;
        ushort4v p;
        if (e < 256000) {  // 500*512 real elements
            const float4 v = *(const float4*)(W_out + e);
            p.x = f2bf(v.x); p.y = f2bf(v.y); p.z = f2bf(v.z); p.w = f2bf(v.w);
        } else {
            p.x = 0; p.y = 0; p.z = 0; p.w = 0;
        }
        *(ushort4v*)(wout_bf + e) = p;
        return;
    }

    // ---- projection: 32 rows x 128 cols per block ----
    const float *A, *W, *bias; float* outp; int Ma, t, jq;
    if (blk < 200) { A = enc_in; W = W_enc; bias = b_enc; outp = enc_proj;
                     Ma = 1600; t = blk >> 2; jq = blk & 3; }
    else           { const int b2 = blk - 200;
                     A = dec_in; W = W_dec; bias = b_dec; outp = dec_proj;
                     Ma = 400;  t = b2 >> 2;  jq = b2 & 3; }
    const int r0 = t * 32;

    __shared__ unsigned short tile[32 * 520];
    {   // stage A fp32->bf16: 8 threads per row
        const int row = tid >> 3, q = tid & 7;
        int gr = r0 + row;
        if (gr >= Ma) gr = Ma - 1;
        const float* src = A + (size_t)gr * 512;
        ushort8* dst = (ushort8*)(tile + row * 520);
        #pragma unroll
        for (int i = 0; i < 8; ++i) {
            const int c = q + i * 8;
            const int k = c * 8;
            const float4 a0 = *(const float4*)(src + k);
            const float4 a1 = *(const float4*)(src + k + 4);
            bfcast pk;
            pk.u[0] = f2bf(a0.x); pk.u[1] = f2bf(a0.y); pk.u[2] = f2bf(a0.z); pk.u[3] = f2bf(a0.w);
            pk.u[4] = f2bf(a1.x); pk.u[5] = f2bf(a1.y); pk.u[6] = f2bf(a1.z); pk.u[7] = f2bf(a1.w);
            dst[c] = pk.u;
        }
    }
    __syncthreads();

    const int wave = tid >> 6, lane = tid & 63;
    const int lrow = lane & 15;
    const int lk8  = (lane >> 4) * 8;
    const int j0   = jq * 128 + wave * 32;

    f32x4 acc[2][2];
    #pragma unroll
    for (int mi = 0; mi < 2; ++mi)
        #pragma unroll
        for (int ji = 0; ji < 2; ++ji)
            acc[mi][ji] = (f32x4){0.f, 0.f, 0.f, 0.f};

    const unsigned short* abase = tile + lrow * 520 + lk8;
    const float* wb0 = W + (size_t)(j0 + lrow) * 512 + lk8;
    const float* wb1 = wb0 + 16 * 512;

    #pragma unroll
    for (int kk = 0; kk < 512; kk += 32) {
        const bf16x8 a0 = *(const bf16x8*)(abase + kk);
        const bf16x8 a1 = *(const bf16x8*)(abase + 16 * 520 + kk);
        const bf16x8 b0 = load_w8_f32(wb0 + kk);
        const bf16x8 b1 = load_w8_f32(wb1 + kk);
        acc[0][0] = __builtin_amdgcn_mfma_f32_16x16x32_bf16(a0, b0, acc[0][0], 0, 0, 0);
        acc[0][1] = __builtin_amdgcn_mfma_f32_16x16x32_bf16(a0, b1, acc[0][1], 0, 0, 0);
        acc[1][0] = __builtin_amdgcn_mfma_f32_16x16x32_bf16(a1, b0, acc[1][0], 0, 0, 0);
        acc[1][1] = __builtin_amdgcn_mfma_f32_16x16x32_bf16(a1, b1, acc[1][1], 0, 0, 0);
    }

    const int crow = (lane >> 4) * 4;
    const int ccol = lane & 15;
    #pragma unroll
    for (int ji = 0; ji < 2; ++ji) {
        const int col = j0 + ji * 16 + ccol;
        const float bv = bias[col];
        #pragma unroll
        for (int mi = 0; mi < 2; ++mi)
            #pragma unroll
            for (int rg = 0; rg < 4; ++rg) {
                const int gr = r0 + mi * 16 + crow + rg;
                if (gr < Ma) outp[(size_t)gr * 512 + col] = acc[mi][ji][rg] + bv;
            }
    }
}

// out[r, v] = sum_k tanh(enc[n,t,k] + dec[n,u,k]) * Wout[v,k] + bout[v]
// 512 thr = 8 waves; BM=80 rows/block (1000 blocks, exact); wave w owns v in
// [w*64, w*64+64), acc[5][4] = 80 AGPR. K-loop/epilogue structure identical
// to the round-4 103.5 us champion (depth-2 B prefetch, LDS-transpose
// epilogue with float4 stores -- R8 proved direct scalar stores regress).
// Round-8 post-mortem: Occupancy(measured)/Occupancy(theoretical) = 0.71 in
// BOTH R4 and R5 -> ~19% structural idle is the GRID TAIL: 625 blocks at
// 1 block/CU residency = ceil(625/256)=3 generations with only 2.44 filled
// (81% util). BM=80 -> 1000 blocks -> 3.91/4 generations = 97.7% util.
// Cost: B-traffic/row 4 -> 6.4 KB (mild, from the measured BM curve).
__global__ __launch_bounds__(512, 2) void joiner_kernel(
    const float* __restrict__ encp,          // 1600 x 512 f32 (ws)
    const float* __restrict__ decp,          // 400 x 512 f32 (ws)
    const unsigned short* __restrict__ Wout, // 512 x 512 bf16, rows >=500 zero (ws)
    const float* __restrict__ bout,          // 500 f32
    float* __restrict__ out)                 // 80000 x 500 f32
{
    __shared__ unsigned short tile[80 * 520];    // 83,200 B; epilogue reuses as 16x516 f32
    const int tid = threadIdx.x;
    const int r0 = blockIdx.x * 80;

    {   // phase 1: x-tile = tanh(enc+dec) -> bf16, 8 threads/row, 64+16 rows
        #pragma unroll
        for (int half = 0; half < 2; ++half) {
            const int row = (tid >> 3) + half * 64;
            if (row < 80) {
                const int q = tid & 7;
                const int r = r0 + row;
                const int n = r / 10000;
                const int rem = r % 10000;
                const int t = rem / 50;
                const int u = rem - t * 50;
                const float* erow = encp + (size_t)(n * 200 + t) * 512;
                const float* drow = decp + (size_t)(n * 50 + u) * 512;
                ushort8* dst = (ushort8*)(tile + row * 520);
                #pragma unroll
                for (int i = 0; i < 8; ++i) {
                    const int c = q + i * 8;
                    const int k = c * 8;
                    const float4 ev0 = *(const float4*)(erow + k);
                    const float4 ev1 = *(const float4*)(erow + k + 4);
                    const float4 dv0 = *(const float4*)(drow + k);
                    const float4 dv1 = *(const float4*)(drow + k + 4);
                    float xs[8] = {ev0.x + dv0.x, ev0.y + dv0.y, ev0.z + dv0.z, ev0.w + dv0.w,
                                   ev1.x + dv1.x, ev1.y + dv1.y, ev1.z + dv1.z, ev1.w + dv1.w};
                    bfcast pk;
                    #pragma unroll
                    for (int j = 0; j < 8; ++j) pk.u[j] = f2bf(fast_tanh(xs[j]));
                    dst[c] = pk.u;
                }
            }
        }
    }
    __syncthreads();

    const int wave = tid >> 6, lane = tid & 63;
    const int lrow = lane & 15;
    const int lk8  = (lane >> 4) * 8;
    const int v0   = wave * 64;

    f32x4 acc[5][4];
    #pragma unroll
    for (int mi = 0; mi < 5; ++mi)
        #pragma unroll
        for (int ji = 0; ji < 4; ++ji)
            acc[mi][ji] = (f32x4){0.f, 0.f, 0.f, 0.f};

    const unsigned short* wrow[4];
    #pragma unroll
    for (int ji = 0; ji < 4; ++ji)
        wrow[ji] = Wout + (size_t)(v0 + ji * 16 + lrow) * 512 + lk8;
    const unsigned short* abase = tile + lrow * 520 + lk8;

    // depth-2 software pipeline on B (L2-resident Wout panel, read once/wave)
    bf16x8 breg[2][4];
    #pragma unroll
    for (int ji = 0; ji < 4; ++ji) breg[0][ji] = *(const bf16x8*)(wrow[ji]);
    #pragma unroll
    for (int ji = 0; ji < 4; ++ji) breg[1][ji] = *(const bf16x8*)(wrow[ji] + 32);

    #pragma unroll
    for (int kk = 0; kk < 16; ++kk) {
        bf16x8 bn[4];
        if (kk < 14) {
            #pragma unroll
            for (int ji = 0; ji < 4; ++ji)
                bn[ji] = *(const bf16x8*)(wrow[ji] + (kk + 2) * 32);
        }
        #pragma unroll
        for (int mi = 0; mi < 5; ++mi) {
            const bf16x8 a = *(const bf16x8*)(abase + mi * 16 * 520 + kk * 32);
            #pragma unroll
            for (int ji = 0; ji < 4; ++ji)
                acc[mi][ji] = __builtin_amdgcn_mfma_f32_16x16x32_bf16(
                    a, breg[kk & 1][ji], acc[mi][ji], 0, 0, 0);
        }
        if (kk < 14) {
            #pragma unroll
            for (int ji = 0; ji < 4; ++ji) breg[kk & 1][ji] = bn[ji];
        }
    }

    // epilogue: five 16-row quarters through LDS, then contiguous float4 stores
    float* ob = (float*)tile;                // 16 rows x stride 516 f32 (33,024 B)
    const int crow = (lane >> 4) * 4;
    const int ccol = lane & 15;
    const int srow = tid >> 5, sslot = tid & 31;   // 16 rows x 32 slots
    #pragma unroll
    for (int h = 0; h < 5; ++h) {
        __syncthreads();   // h=0: all K-loop tile reads done; else: prev stores done
        #pragma unroll
        for (int ji = 0; ji < 4; ++ji) {
            const int v = v0 + ji * 16 + ccol;
            const float bv = (v < 500) ? bout[v] : 0.f;
            #pragma unroll
            for (int rg = 0; rg < 4; ++rg)
                ob[(crow + rg) * 516 + v] = acc[h][ji][rg] + bv;
        }
        __syncthreads();
        const size_t gr = (size_t)(r0 + h * 16 + srow);
        const float* src = ob + srow * 516;
        float* drow = out + gr * 500;
        #pragma unroll
        for (int i = 0; i < 4; ++i) {
            const int c = sslot + 32 * i;
            if (c < 125)
                *(float4*)(drow + c * 4) = *(const float4*)(src + c * 4);
        }
    }
}

extern "C" void kernel_launch(void* const* d_in, const int* in_sizes, int n_in,
                              void* d_out, int out_size, void* d_ws, size_t ws_size,
                              hipStream_t stream) {
    (void)in_sizes; (void)n_in; (void)out_size; (void)ws_size;
    const float* enc_in = (const float*)d_in[0]; // 8x200x512 f32
    const float* dec_in = (const float*)d_in[1]; // 8x50x512 f32
    const float* W_enc  = (const float*)d_in[2]; // 512x512 f32
    const float* b_enc  = (const float*)d_in[3]; // 512 f32
    const float* W_dec  = (const float*)d_in[4]; // 512x512 f32
    const float* b_dec  = (const float*)d_in[5]; // 512 f32
    const float* W_out  = (const float*)d_in[6]; // 500x512 f32
    const float* b_out  = (const float*)d_in[7]; // 500 f32
    float* out = (float*)d_out;                  // 8x200x50x500 f32

    float* ws = (float*)d_ws;
    float* enc_proj = ws;                                      // 1600*512 f32
    float* dec_proj = ws + 819200;                             // 400*512 f32
    unsigned short* wout_bf = (unsigned short*)(ws + 1024000); // 512*512 bf16 (padded)

    hipLaunchKernelGGL(prep_kernel, dim3(508), dim3(256), 0, stream,
                       enc_in, dec_in, W_enc, b_enc, W_dec, b_dec, W_out,
                       enc_proj, dec_proj, wout_bf);
    hipLaunchKernelGGL(joiner_kernel, dim3(1000), dim3(512), 0, stream,
                       enc_proj, dec_proj, wout_bf, b_out, out);
}